// Round 17
// baseline (1338.495 us; speedup 1.0000x reference)
//
#include <hip/hip_runtime.h>
#include <hip/hip_bf16.h>

typedef __attribute__((ext_vector_type(4))) float f32x4;
typedef __attribute__((ext_vector_type(8))) short bf16x8;
typedef __attribute__((ext_vector_type(8))) unsigned short us8;
typedef unsigned int   u32;
typedef unsigned short u16;

#define D_DIM 2048
#define I_DIM 768
#define NE    64
#define CAP   1024
#define NTOK  4096

__device__ __forceinline__ u32 cvt2(float a, float b) {
  __hip_bfloat162 hh = __float22bfloat162_rn(float2{a, b});
  union { __hip_bfloat162 h; u32 u; } c; c.h = hh; return c.u;
}
__device__ __forceinline__ u16 f2b(float f) {
  __hip_bfloat16 b = __float2bfloat16(f);
  union { __hip_bfloat16 b; u16 u; } c; c.b = b; return c.u;
}
__device__ __forceinline__ float b2f(u16 v) {
  union { u32 u; float f; } c; c.u = (u32)v << 16; return c.f;
}
// async global->LDS, 16B per lane. LDS dest = wave-uniform base + lane*16.
__device__ __forceinline__ void glp16(const void* g, void* l) {
  __builtin_amdgcn_global_load_lds(
      (const __attribute__((address_space(1))) u32*)g,
      (__attribute__((address_space(3))) u32*)l, 16, 0, 0);
}

#define VMW(n) asm volatile("s_waitcnt vmcnt(" #n ")" ::: "memory")
#define LGK    asm volatile("s_waitcnt lgkmcnt(0)" ::: "memory")
#define BARF   do { __builtin_amdgcn_s_barrier(); \
                    asm volatile("" ::: "memory"); } while (0)

// ---------------- router: fp32 logits, top-8, renorm, dispatch + bf16 x copy --
__global__ __launch_bounds__(256) void k_router(
    const float* __restrict__ x, const float* __restrict__ rw,
    int* __restrict__ counts, int* __restrict__ slot_token,
    float* __restrict__ slot_w, u16* __restrict__ xb)
{
  const int lane = threadIdx.x & 63;
  const int tok  = blockIdx.x * 4 + (threadIdx.x >> 6);
  const float* xr = x + (size_t)tok * D_DIM;
  u16* xbr = xb + (size_t)tok * D_DIM;

  float acc = 0.f;
  for (int d0 = 0; d0 < D_DIM; d0 += 64) {
    float xv = xr[d0 + lane];
    xbr[d0 + lane] = f2b(xv);
    #pragma unroll
    for (int j = 0; j < 64; ++j) {
      float xj = __shfl(xv, j, 64);
      acc = fmaf(xj, rw[(size_t)(d0 + j) * NE + lane], acc);
    }
  }

  float v = acc; int vi = lane;
  float wk[8]; int ei[8];
  float mx0 = 0.f, wsum = 0.f;
  #pragma unroll
  for (int k = 0; k < 8; ++k) {
    float mv = v; int mi = vi;
    #pragma unroll
    for (int off = 32; off >= 1; off >>= 1) {
      float ov = __shfl_xor(mv, off, 64);
      int   oi = __shfl_xor(mi, off, 64);
      if (ov > mv || (ov == mv && oi < mi)) { mv = ov; mi = oi; }
    }
    if (k == 0) mx0 = mv;
    float ew = __expf(mv - mx0);
    wk[k] = ew; ei[k] = mi; wsum += ew;
    if (lane == mi) v = -3.4e38f;
  }

  if (lane == 0) {
    float inv = 1.f / wsum;
    #pragma unroll
    for (int k = 0; k < 8; ++k) {
      int ee   = ei[k];
      int slot = atomicAdd(&counts[ee], 1);
      if (slot < CAP) {
        slot_token[ee * CAP + slot] = tok;
        slot_w[ee * CAP + slot]     = wk[k] * inv;
      }
    }
  }
}

// ---------------- inverse map: (e,slot) -> per-token index list --------------
__global__ __launch_bounds__(256) void k_inv(
    const int* __restrict__ counts, const int* __restrict__ slot_token,
    int* __restrict__ tok_cnt, int* __restrict__ tok_idx)
{
  const int e = blockIdx.x;
  int cnt = counts[e]; if (cnt > CAP) cnt = CAP;
  for (int s = threadIdx.x; s < cnt; s += 256) {
    const int tok = slot_token[e * CAP + s];
    const int pos = atomicAdd(&tok_cnt[tok], 1);
    if (pos < 8) tok_idx[tok * 8 + pos] = e * CAP + s;
  }
}

// ---------------- x pack: gather tokens -> xeT[e][kcell(256)][1024][8] --------
__global__ __launch_bounds__(256) void k_xpack(
    const u16* __restrict__ xb, const int* __restrict__ counts,
    const int* __restrict__ slot_token, u16* __restrict__ xeT)
{
  const int e   = blockIdx.z;
  const int s0  = blockIdx.y * 64;
  const int kc0 = blockIdx.x * 32;
  int cnt = counts[e]; if (cnt > CAP) cnt = CAP;
  const int lim = (cnt + 127) & ~127;
  if (s0 >= lim) return;

  __shared__ u16 T[64][264];
  const int t = threadIdx.x;
  const int r = t >> 2;
  const int q = t & 3;
  const int  tok  = slot_token[e * CAP + s0 + r];
  const bool live = (s0 + r) < cnt;
  const u16* src = xb + (size_t)tok * D_DIM + kc0 * 8;

  #pragma unroll
  for (int it = 0; it < 8; ++it) {
    const int kl = it * 32 + q * 8;
    us8 v = {0, 0, 0, 0, 0, 0, 0, 0};
    if (live) v = *(const us8*)(src + kl);
    *(us8*)&T[r][kl] = v;
  }
  __syncthreads();

  u16* dst = xeT + (size_t)e * 2097152 + (size_t)kc0 * 8192 + (size_t)s0 * 8;
  const int sl = t & 63;
  #pragma unroll
  for (int p = 0; p < 8; ++p) {
    const int c = (t >> 6) + p * 4;
    const u16* s = &T[sl][c * 8];
    uint4 o = *(const uint4*)s;
    *(uint4*)(dst + (size_t)c * 8192 + sl * 8) = o;
  }
}

// ====== GEMMs: direct fp32 weights, T14 issue-early/write-late staging ========
// LDS: A bf16 ring-3 (glp) @0 (3x4096 u16); B bf16 ring-2 @12288 (2x8192 u16).
// Per phase: issue B fp32 loads(j+1) + A glps(j+2); ds_read+MFMA stage j;
// vmcnt(0); cvt+ds_write B(j+1); lgkmcnt(0); barrier.

// ---- mlp1: tile 128m x 128i (gate+up), wave = 64m x 64i x {g,u} ----
__device__ __forceinline__ void m1_step(
    const u16* sm, int ra, int rb, int gq, int li, int mrow, int icol,
    f32x4 (&ag)[4][4], f32x4 (&au)[4][4])
{
  const u16* sa = sm + ra * 4096;
  const u16* sb = sm + 12288 + rb * 8192;
  bf16x8 a[4], g[4], u[4];
  #pragma unroll
  for (int mf = 0; mf < 4; ++mf)
    a[mf] = *(const bf16x8*)&sa[(gq * 128 + mrow + mf * 16 + li) * 8];
  #pragma unroll
  for (int nf = 0; nf < 4; ++nf) {
    g[nf] = *(const bf16x8*)&sb[(gq * 128 + icol + nf * 16 + li) * 8];
    u[nf] = *(const bf16x8*)&sb[4096 + (gq * 128 + icol + nf * 16 + li) * 8];
  }
  #pragma unroll
  for (int mf = 0; mf < 4; ++mf)
    #pragma unroll
    for (int nf = 0; nf < 4; ++nf) {
      ag[mf][nf] = __builtin_amdgcn_mfma_f32_16x16x32_bf16(a[mf], g[nf], ag[mf][nf], 0, 0, 0);
      au[mf][nf] = __builtin_amdgcn_mfma_f32_16x16x32_bf16(a[mf], u[nf], au[mf][nf], 0, 0, 0);
    }
}

// grid 3072 (8mt x 6nt x 64e), XCD-swizzled, 56KB dyn LDS.
__global__ __launch_bounds__(256, 2) void k_mlp1p(
    const u16* __restrict__ xeT, const float* __restrict__ gate,
    const float* __restrict__ up, const int* __restrict__ counts,
    u16* __restrict__ hP)
{
  extern __shared__ u16 sm[];
  const int i   = blockIdx.x;
  const int xcd = i & 7;
  const int p   = i >> 3;
  const int mt  = p & 7;
  const int pe  = p >> 3;
  const int val = pe * 8 + xcd;        // == e*6 + nt
  const int e   = val / 6;
  const int nt  = val % 6;

  int cnt = counts[e]; if (cnt > CAP) cnt = CAP;
  const int m0 = mt * 128;
  if (m0 >= cnt) return;
  const int i0 = nt * 128;

  const int t = threadIdx.x;
  const int lane = t & 63, wv = t >> 6;
  const int li = lane & 15, gq = lane >> 4;
  const int mrow = (wv >> 1) * 64, icol = (wv & 1) * 64;

  // A staging (glp): wave wv owns kc=wv, halves h=0,1
  const u16* ap = xeT + (size_t)e * 2097152;
  const int a0off = (m0 + lane) * 8;
  const int a1off = (m0 + 64 + lane) * 8;

  // B staging (fp32 direct): thread -> tensor tn, k-group kg, i-quad qq
  const int tn = t >> 7;
  const int tt = t & 127;
  const int kg = tt >> 5;
  const int qq = tt & 31;
  const float* bp = (tn ? up : gate) + (size_t)e * D_DIM * I_DIM
                    + (size_t)(kg * 8) * I_DIM + i0 + qq * 4;
  const int bwr = 12288 + tn * 4096 + kg * 1024 + qq * 32;   // + rbn*8192

  f32x4 ag[4][4], au[4][4];
  #pragma unroll
  for (int mf = 0; mf < 4; ++mf)
    #pragma unroll
    for (int nf = 0; nf < 4; ++nf) {
      f32x4 z = {0.f, 0.f, 0.f, 0.f};
      ag[mf][nf] = z; au[mf][nf] = z;
    }

  float4 c0, c1, c2, c3, c4, c5, c6, c7;

#define M1_ISSA(RA) do {                                          \
    glp16(ap + (size_t)wv * 8192 + a0off, sm + (RA) * 4096 + wv * 1024);        \
    glp16(ap + (size_t)wv * 8192 + a1off, sm + (RA) * 4096 + wv * 1024 + 512);  \
    ap += 32768; } while (0)

#define M1_ISSB() do {                                            \
    c0 = *(const float4*)(bp);                                    \
    c1 = *(const float4*)(bp + I_DIM);                            \
    c2 = *(const float4*)(bp + 2 * I_DIM);                        \
    c3 = *(const float4*)(bp + 3 * I_DIM);                        \
    c4 = *(const float4*)(bp + 4 * I_DIM);                        \
    c5 = *(const float4*)(bp + 5 * I_DIM);                        \
    c6 = *(const float4*)(bp + 6 * I_DIM);                        \
    c7 = *(const float4*)(bp + 7 * I_DIM);                        \
    bp += 32 * I_DIM; } while (0)

#define M1_WRB(RBN) do {                                          \
    u16* d = sm + bwr + (RBN) * 8192;                             \
    uint4 o;                                                      \
    o.x = cvt2(c0.x, c1.x); o.y = cvt2(c2.x, c3.x);               \
    o.z = cvt2(c4.x, c5.x); o.w = cvt2(c6.x, c7.x);               \
    *(uint4*)(d) = o;                                             \
    o.x = cvt2(c0.y, c1.y); o.y = cvt2(c2.y, c3.y);               \
    o.z = cvt2(c4.y, c5.y); o.w = cvt2(c6.y, c7.y);               \
    *(uint4*)(d + 8) = o;                                         \
    o.x = cvt2(c0.z, c1.z); o.y = cvt2(c2.z, c3.z);               \
    o.z = cvt2(c4.z, c5.z); o.w = cvt2(c6.z, c7.z);               \
    *(uint4*)(d + 16) = o;                                        \
    o.x = cvt2(c0.w, c1.w); o.y = cvt2(c2.w, c3.w);               \
    o.z = cvt2(c4.w, c5.w); o.w = cvt2(c6.w, c7.w);               \
    *(uint4*)(d + 24) = o; } while (0)

#define M1_PH(RA, RB, RBN, RAN) do {                              \
    M1_ISSB(); M1_ISSA(RAN);                                      \
    m1_step(sm, RA, RB, gq, li, mrow, icol, ag, au);              \
    VMW(0);                                                       \
    M1_WRB(RBN);                                                  \
    LGK; BARF; } while (0)

  // prologue: A(0), A(1) glps; B(0) loads; drain; write B(0) ring0
  M1_ISSA(0); M1_ISSA(1);
  M1_ISSB();
  VMW(0);
  M1_WRB(0);
  LGK; BARF;

  // main: j = 0..59 (10 x period-6)
  for (int jt = 0; jt < 10; ++jt) {
    M1_PH(0, 0, 1, 2);
    M1_PH(1, 1, 0, 0);
    M1_PH(2, 0, 1, 1);
    M1_PH(0, 1, 0, 2);
    M1_PH(1, 0, 1, 0);
    M1_PH(2, 1, 0, 1);
  }
  // j=60, 61
  M1_PH(0, 0, 1, 2);
  M1_PH(1, 1, 0, 0);
  // j=62: issue B(63) only
  M1_ISSB();
  m1_step(sm, 2, 0, gq, li, mrow, icol, ag, au);
  VMW(0);
  M1_WRB(1);
  LGK; BARF;
  // j=63
  m1_step(sm, 0, 1, gq, li, mrow, icol, ag, au);

#undef M1_PH
#undef M1_WRB
#undef M1_ISSB
#undef M1_ISSA

  // epilogue: h = silu(g)*u, packed hP[e][ii>>3][slot][ii&7]; live slots only
  u16* hPe = hP + (size_t)e * 786432;
  #pragma unroll
  for (int mf = 0; mf < 4; ++mf)
    #pragma unroll
    for (int jj = 0; jj < 4; ++jj) {
      const int slot = m0 + mrow + mf * 16 + gq * 4 + jj;
      if (slot < cnt) {
        #pragma unroll
        for (int nf = 0; nf < 4; ++nf) {
          const int ii = nt * 128 + icol + nf * 16 + li;
          float gg = ag[mf][nf][jj];
          float uu = au[mf][nf][jj];
          hPe[(size_t)(ii >> 3) * 8192 + slot * 8 + (ii & 7)] =
              f2b(gg * uu / (1.f + __expf(-gg)));
        }
      }
    }
}

// ---- mlp2: tile 128m x 256n, wave = 64m x 128n ----
__device__ __forceinline__ void m2_step(
    const u16* sm, int ra, int rb, int gq, int li, int mrow, int ncol,
    f32x4 (&acc)[4][8])
{
  const u16* sa = sm + ra * 4096;
  const u16* sb = sm + 12288 + rb * 8192;
  bf16x8 a[4], b[8];
  #pragma unroll
  for (int mf = 0; mf < 4; ++mf)
    a[mf] = *(const bf16x8*)&sa[(gq * 128 + mrow + mf * 16 + li) * 8];
  #pragma unroll
  for (int nf = 0; nf < 8; ++nf)
    b[nf] = *(const bf16x8*)&sb[(gq * 256 + ncol + nf * 16 + li) * 8];
  #pragma unroll
  for (int mf = 0; mf < 4; ++mf)
    #pragma unroll
    for (int nf = 0; nf < 8; ++nf)
      acc[mf][nf] = __builtin_amdgcn_mfma_f32_16x16x32_bf16(a[mf], b[nf], acc[mf][nf], 0, 0, 0);
}

// grid 4096 (8mt x 8nt x 64e), XCD-swizzled, 56KB dyn LDS.
__global__ __launch_bounds__(256, 2) void k_mlp2p(
    const u16* __restrict__ hP, const float* __restrict__ down,
    const int* __restrict__ counts, const float* __restrict__ slot_w,
    u16* __restrict__ ye)
{
  extern __shared__ u16 sm[];
  const int i   = blockIdx.x;
  const int xcd = i & 7;
  const int p   = i >> 3;
  const int mt  = p & 7;
  const int pe  = p >> 3;
  const int val = pe * 8 + xcd;        // == e*8 + nt
  const int e   = val >> 3;
  const int nt  = val & 7;

  int cnt = counts[e]; if (cnt > CAP) cnt = CAP;
  const int m0 = mt * 128;
  if (m0 >= cnt) return;
  const int n0 = nt * 256;

  const int t = threadIdx.x;
  const int lane = t & 63, wv = t >> 6;
  const int li = lane & 15, gq = lane >> 4;
  const int mrow = (wv >> 1) * 64, ncol = (wv & 1) * 128;

  const u16* ap = hP + (size_t)e * 786432;
  const int a0off = (m0 + lane) * 8;
  const int a1off = (m0 + 64 + lane) * 8;

  const int kg = t >> 6;
  const int qq = t & 63;
  const float* bp = down + (size_t)e * I_DIM * D_DIM
                    + (size_t)(kg * 8) * D_DIM + n0 + qq * 4;
  const int bwr = 12288 + kg * 2048 + qq * 32;

  const int eCAP = e * CAP;

  f32x4 acc[4][8];
  #pragma unroll
  for (int mf = 0; mf < 4; ++mf)
    #pragma unroll
    for (int nf = 0; nf < 8; ++nf) { f32x4 z = {0.f,0.f,0.f,0.f}; acc[mf][nf] = z; }

  float4 c0, c1, c2, c3, c4, c5, c6, c7;

#define M2_ISSA(RA) do {                                          \
    glp16(ap + (size_t)wv * 8192 + a0off, sm + (RA) * 4096 + wv * 1024);        \
    glp16(ap + (size_t)wv * 8192 + a1off, sm + (RA) * 4096 + wv * 1024 + 512);  \
    ap += 32768; } while (0)

#define M2_ISSB() do {                                            \
    c0 = *(const float4*)(bp);                                    \
    c1 = *(const float4*)(bp + D_DIM);                            \
    c2 = *(const float4*)(bp + 2 * D_DIM);                        \
    c3 = *(const float4*)(bp + 3 * D_DIM);                        \
    c4 = *(const float4*)(bp + 4 * D_DIM);                        \
    c5 = *(const float4*)(bp + 5 * D_DIM);                        \
    c6 = *(const float4*)(bp + 6 * D_DIM);                        \
    c7 = *(const float4*)(bp + 7 * D_DIM);                        \
    bp += 32 * D_DIM; } while (0)

#define M2_WRB(RBN) do {                                          \
    u16* d = sm + bwr + (RBN) * 8192;                             \
    uint4 o;                                                      \
    o.x = cvt2(c0.x, c1.x); o.y = cvt2(c2.x, c3.x);               \
    o.z = cvt2(c4.x, c5.x); o.w = cvt2(c6.x, c7.x);               \
    *(uint4*)(d) = o;                                             \
    o.x = cvt2(c0.y, c1.y); o.y = cvt2(c2.y, c3.y);               \
    o.z = cvt2(c4.y, c5.y); o.w = cvt2(c6.y, c7.y);               \
    *(uint4*)(d + 8) = o;                                         \
    o.x = cvt2(c0.z, c1.z); o.y = cvt2(c2.z, c3.z);               \
    o.z = cvt2(c4.z, c5.z); o.w = cvt2(c6.z, c7.z);               \
    *(uint4*)(d + 16) = o;                                        \
    o.x = cvt2(c0.w, c1.w); o.y = cvt2(c2.w, c3.w);               \
    o.z = cvt2(c4.w, c5.w); o.w = cvt2(c6.w, c7.w);               \
    *(uint4*)(d + 24) = o; } while (0)

#define M2_PH(RA, RB, RBN, RAN) do {                              \
    M2_ISSB(); M2_ISSA(RAN);                                      \
    m2_step(sm, RA, RB, gq, li, mrow, ncol, acc);                 \
    VMW(0);                                                       \
    M2_WRB(RBN);                                                  \
    LGK; BARF; } while (0)

  // prologue
  M2_ISSA(0); M2_ISSA(1);
  M2_ISSB();
  VMW(0);
  M2_WRB(0);
  LGK; BARF;

  // main: j = 0..17 (3 x period-6)
  for (int jt = 0; jt < 3; ++jt) {
    M2_PH(0, 0, 1, 2);
    M2_PH(1, 1, 0, 0);
    M2_PH(2, 0, 1, 1);
    M2_PH(0, 1, 0, 2);
    M2_PH(1, 0, 1, 0);
    M2_PH(2, 1, 0, 1);
  }
  // j=18..21
  M2_PH(0, 0, 1, 2);
  M2_PH(1, 1, 0, 0);
  M2_PH(2, 0, 1, 1);
  M2_PH(0, 1, 0, 2);
  // j=22: issue B(23) only
  M2_ISSB();
  m2_step(sm, 1, 0, gq, li, mrow, ncol, acc);
  VMW(0);
  M2_WRB(1);
  LGK; BARF;
  // j=23
  m2_step(sm, 2, 1, gq, li, mrow, ncol, acc);

#undef M2_PH
#undef M2_WRB
#undef M2_ISSB
#undef M2_ISSA

  #pragma unroll
  for (int mf = 0; mf < 4; ++mf)
    #pragma unroll
    for (int jj = 0; jj < 4; ++jj) {
      const int slot = m0 + mrow + mf * 16 + gq * 4 + jj;
      if (slot < cnt) {
        const float wgt = slot_w[eCAP + slot];
        u16* yr = ye + (size_t)(eCAP + slot) * D_DIM + n0 + ncol + li;
        #pragma unroll
        for (int nf = 0; nf < 8; ++nf)
          yr[nf * 16] = f2b(wgt * acc[mf][nf][jj]);
      }
    }
}

// ---------------- combine: out[tok] = sum_k ye[tok_idx[tok][k]] --------------
__global__ __launch_bounds__(256) void k_combine(
    const u16* __restrict__ ye, const int* __restrict__ tok_idx,
    const int* __restrict__ tok_cnt, float* __restrict__ out)
{
  const int tok = blockIdx.x;
  const int c0  = threadIdx.x * 8;
  int cnt8 = tok_cnt[tok]; if (cnt8 > 8) cnt8 = 8;

  float s[8] = {0.f, 0.f, 0.f, 0.f, 0.f, 0.f, 0.f, 0.f};
  #pragma unroll
  for (int k = 0; k < 8; ++k) {
    if (k < cnt8) {
      const int idx = tok_idx[tok * 8 + k];
      const us8 v = *(const us8*)(ye + (size_t)idx * D_DIM + c0);
      #pragma unroll
      for (int j = 0; j < 8; ++j) s[j] += b2f(v[j]);
    }
  }
  float4 o0 = {s[0], s[1], s[2], s[3]};
  float4 o1 = {s[4], s[5], s[6], s[7]};
  float* op = out + (size_t)tok * D_DIM + c0;
  *(float4*)op       = o0;
  *(float4*)(op + 4) = o1;
}

extern "C" void kernel_launch(void* const* d_in, const int* in_sizes, int n_in,
                              void* d_out, int out_size, void* d_ws, size_t ws_size,
                              hipStream_t stream) {
  const float* x    = (const float*)d_in[0];
  const float* rw   = (const float*)d_in[1];
  const float* gate = (const float*)d_in[2];
  const float* up   = (const float*)d_in[3];
  const float* down = (const float*)d_in[4];
  float* out = (float*)d_out;

  char* ws = (char*)d_ws;
  int*   counts     = (int*)ws;
  int*   slot_token = (int*)(ws + 1024);
  float* slot_w     = (float*)(ws + 263168);
  u16*   xb         = (u16*)(ws + 525312);
  u16*   hP         = (u16*)(ws + 17302528);          // 100.66 MB
  u16*   ye         = (u16*)(ws + 117965824);         // 268.4 MB (old Gpk/Upk)
  u16*   xeT        = (u16*)(ws + 520619008);         // 268.4 MB
  int*   tok_cnt    = (int*)(ws + 721945600);
  int*   tok_idx    = (int*)(ws + 721945600 + 16384);

  // allow 56 KB dynamic LDS (host-side attr set; graph-safe)
  hipFuncSetAttribute((const void*)k_mlp1p,
                      hipFuncAttributeMaxDynamicSharedMemorySize, 57344);
  hipFuncSetAttribute((const void*)k_mlp2p,
                      hipFuncAttributeMaxDynamicSharedMemorySize, 57344);

  hipMemsetAsync(counts, 0, NE * sizeof(int), stream);
  hipMemsetAsync(slot_token, 0, (size_t)NE * CAP * sizeof(int), stream);

  k_router<<<dim3(NTOK / 4), 256, 0, stream>>>(x, rw, counts, slot_token, slot_w, xb);
  k_xpack<<<dim3(8, 16, NE), 256, 0, stream>>>(xb, counts, slot_token, xeT);
  k_mlp1p<<<dim3(3072), 256, 57344, stream>>>(xeT, gate, up, counts, hP);

  hipMemsetAsync(tok_cnt, 0, NTOK * sizeof(int), stream);
  k_inv<<<dim3(NE), 256, 0, stream>>>(counts, slot_token, tok_cnt, tok_idx);

  k_mlp2p  <<<dim3(4096), 256, 57344, stream>>>(hP, down, counts, slot_w, ye);
  k_combine<<<dim3(NTOK), 256, 0, stream>>>(ye, tok_idx, tok_cnt, out);
}